// Round 1
// baseline (358.384 us; speedup 1.0000x reference)
//
#include <hip/hip_runtime.h>
#include <hip/hip_bf16.h>

// CoPE, bf16 I/O (device-detected; f32 path kept). dur_us carries ~234us of
// harness fill/restore floor; our budget is the kernels themselves.
// k1 (cope_li): li[rows][64] f32 = q @ pos_emb into d_ws (amortizes pos_emb
//   staging over 64 rows).
// k2 (cope_row4): NEW wave-per-row shape: 1 block = 4 rows, 1 wave per row,
//   16 cols/lane. Scan is wave-local (6 shfl/row vs 24 before), ZERO
//   __syncthreads (li staged+read by the same wave; lgkmcnt ordering only),
//   32B/lane loads/stores. 12288 blocks instead of 49152.

__device__ __forceinline__ float bf2f(unsigned short u) {
    union { unsigned int i; float f; } t; t.i = ((unsigned int)u) << 16; return t.f;
}
__device__ __forceinline__ float bf2f_lo(unsigned int v) {
    union { unsigned int i; float f; } t; t.i = v << 16; return t.f;
}
__device__ __forceinline__ float bf2f_hi(unsigned int v) {
    union { unsigned int i; float f; } t; t.i = v & 0xffff0000u; return t.f;
}
__device__ __forceinline__ unsigned short f2bf(float f) {
    union { float f; unsigned int i; } t; t.f = f;
    unsigned int lsb = (t.i >> 16) & 1u;
    t.i += 0x7fffu + lsb;
    return (unsigned short)(t.i >> 16);
}
__device__ __forceinline__ float sigmoid_fast(float x) {
    float e = __builtin_amdgcn_exp2f(-1.44269504f * x);
    return __builtin_amdgcn_rcpf(1.0f + e);
}

__global__ __launch_bounds__(256) void cope_detect(
    const unsigned short* __restrict__ q, int* __restrict__ flag)
{
    const int tid = threadIdx.x;
    unsigned short u = q[2 * tid];
    int e = (u >> 7) & 0xFF;
    unsigned long long m = __ballot(e >= 200);
    __shared__ int cnt;
    if (tid == 0) cnt = 0;
    __syncthreads();
    if ((tid & 63) == 0) atomicAdd(&cnt, __popcll(m));
    __syncthreads();
    if (tid == 0) *flag = (cnt > 8) ? 1 : 0;   // 1 => float32 buffers
}

// ---------------------------------------------------------------------------
// k1: li[r][n] = sum_d q[r][d] * pe[d][n].  64 rows/block, 256 thr, 4x4 tile.
// ---------------------------------------------------------------------------
__global__ __launch_bounds__(256) void cope_li(
    const void* __restrict__ qv, const void* __restrict__ pev,
    float* __restrict__ li, const int* __restrict__ flag)
{
    __shared__ float pe_f[64 * 64];   // [d][n]
    __shared__ float q_t[64 * 64];    // [d][r_local]
    const int tid = threadIdx.x;
    const bool isf32 = (*flag != 0);

    if (isf32) {
        const float4* pe4 = reinterpret_cast<const float4*>(pev);
#pragma unroll
        for (int it = 0; it < 4; ++it)
            reinterpret_cast<float4*>(pe_f)[it * 256 + tid] = pe4[it * 256 + tid];
        const float4* q4 = reinterpret_cast<const float4*>(qv) + (size_t)blockIdx.x * 1024;
#pragma unroll
        for (int it = 0; it < 4; ++it) {
            int idx = it * 256 + tid;
            int d4 = idx >> 6, rr = idx & 63;
            float4 v = q4[rr * 16 + d4];
            q_t[(d4 * 4 + 0) * 64 + rr] = v.x;
            q_t[(d4 * 4 + 1) * 64 + rr] = v.y;
            q_t[(d4 * 4 + 2) * 64 + rr] = v.z;
            q_t[(d4 * 4 + 3) * 64 + rr] = v.w;
        }
    } else {
        const uint4* pe16 = reinterpret_cast<const uint4*>(pev);
#pragma unroll
        for (int it = 0; it < 2; ++it) {
            int idx = it * 256 + tid;       // 512 uint4 = 4096 bf16
            uint4 v = pe16[idx];
            float4 a, b;
            a.x = bf2f_lo(v.x); a.y = bf2f_hi(v.x);
            a.z = bf2f_lo(v.y); a.w = bf2f_hi(v.y);
            b.x = bf2f_lo(v.z); b.y = bf2f_hi(v.z);
            b.z = bf2f_lo(v.w); b.w = bf2f_hi(v.w);
            float4* dst = reinterpret_cast<float4*>(&pe_f[idx * 8]);
            dst[0] = a; dst[1] = b;
        }
        const ushort4* q4 = reinterpret_cast<const ushort4*>(qv) + (size_t)blockIdx.x * 1024;
#pragma unroll
        for (int it = 0; it < 4; ++it) {
            int idx = it * 256 + tid;
            int d4 = idx >> 6, rr = idx & 63;
            ushort4 v = q4[rr * 16 + d4];
            q_t[(d4 * 4 + 0) * 64 + rr] = bf2f(v.x);
            q_t[(d4 * 4 + 1) * 64 + rr] = bf2f(v.y);
            q_t[(d4 * 4 + 2) * 64 + rr] = bf2f(v.z);
            q_t[(d4 * 4 + 3) * 64 + rr] = bf2f(v.w);
        }
    }
    __syncthreads();

    const int r0 = (tid & 15) * 4, n0 = (tid >> 4) * 4;
    float acc[4][4];
#pragma unroll
    for (int a = 0; a < 4; ++a)
#pragma unroll
        for (int b = 0; b < 4; ++b) acc[a][b] = 0.f;

#pragma unroll 8
    for (int d = 0; d < 64; ++d) {
        float4 qv4 = *reinterpret_cast<const float4*>(&q_t[d * 64 + r0]);
        float4 pv = *reinterpret_cast<const float4*>(&pe_f[d * 64 + n0]);
        acc[0][0] += qv4.x * pv.x; acc[0][1] += qv4.x * pv.y; acc[0][2] += qv4.x * pv.z; acc[0][3] += qv4.x * pv.w;
        acc[1][0] += qv4.y * pv.x; acc[1][1] += qv4.y * pv.y; acc[1][2] += qv4.y * pv.z; acc[1][3] += qv4.y * pv.w;
        acc[2][0] += qv4.z * pv.x; acc[2][1] += qv4.z * pv.y; acc[2][2] += qv4.z * pv.z; acc[2][3] += qv4.z * pv.w;
        acc[3][0] += qv4.w * pv.x; acc[3][1] += qv4.w * pv.y; acc[3][2] += qv4.w * pv.z; acc[3][3] += qv4.w * pv.w;
    }
#pragma unroll
    for (int a = 0; a < 4; ++a) {
        size_t row = (size_t)blockIdx.x * 64 + r0 + a;
        float4 o; o.x = acc[a][0]; o.y = acc[a][1]; o.z = acc[a][2]; o.w = acc[a][3];
        *reinterpret_cast<float4*>(&li[row * 64 + n0]) = o;
    }
}

// ---------------------------------------------------------------------------
// k2: 1 block = 4 rows, 1 wave per row, 16 cols per lane. NO barriers.
// ---------------------------------------------------------------------------
__global__ __launch_bounds__(256) void cope_row4(
    const void* __restrict__ attnv,
    const float* __restrict__ li_ws,
    void* __restrict__ outv,
    const int* __restrict__ flag,
    const int rows)
{
    const int tid = threadIdx.x;
    const int lane = tid & 63;
    const int wid = tid >> 6;
    const long r = (long)blockIdx.x * 4 + wid;    // this wave's row
    if (r >= rows) return;
    const int i = (int)(r & 1023);                // diagonal column
    const bool isf32 = (*flag != 0);

    __shared__ float li[4][65];                   // per-wave row, +1 pad (li[64]=li[63])

    // Stage this wave's li row. Written and read by the SAME wave ->
    // lgkmcnt ordering suffices, no __syncthreads anywhere in this kernel.
    {
        float lv = li_ws[(size_t)r * 64 + lane];
        li[wid][lane] = lv;
        if (lane == 63) li[wid][64] = lv;
    }

    float g[16];
    if (isf32) {
        const float4* a4 = reinterpret_cast<const float4*>(attnv) + (size_t)r * 256 + lane * 4;
#pragma unroll
        for (int k = 0; k < 4; ++k) {
            float4 v = a4[k];
            g[k * 4 + 0] = sigmoid_fast(v.x);
            g[k * 4 + 1] = sigmoid_fast(v.y);
            g[k * 4 + 2] = sigmoid_fast(v.z);
            g[k * 4 + 3] = sigmoid_fast(v.w);
        }
    } else {
        const uint4* a8 = reinterpret_cast<const uint4*>(attnv) + (size_t)r * 128 + lane * 2;
#pragma unroll
        for (int k = 0; k < 2; ++k) {
            uint4 v = a8[k];
            g[k * 8 + 0] = sigmoid_fast(bf2f_lo(v.x)); g[k * 8 + 1] = sigmoid_fast(bf2f_hi(v.x));
            g[k * 8 + 2] = sigmoid_fast(bf2f_lo(v.y)); g[k * 8 + 3] = sigmoid_fast(bf2f_hi(v.y));
            g[k * 8 + 4] = sigmoid_fast(bf2f_lo(v.z)); g[k * 8 + 5] = sigmoid_fast(bf2f_hi(v.z));
            g[k * 8 + 6] = sigmoid_fast(bf2f_lo(v.w)); g[k * 8 + 7] = sigmoid_fast(bf2f_hi(v.w));
        }
    }

    const int j0 = lane * 16;
    if (i >= j0 && i < j0 + 16) g[i - j0] = 0.f;  // zero diagonal

    float ts = 0.f;
#pragma unroll
    for (int e = 0; e < 16; ++e) ts += g[e];

    // wave-inclusive scan of per-lane sums (entire row lives in one wave)
    float x = ts;
#pragma unroll
    for (int s = 1; s < 64; s <<= 1) {
        float y = __shfl_up(x, s, 64);
        if (lane >= s) x += y;
    }
    const float total = __shfl(x, 63, 64);
    float run = x - ts;                           // exclusive prefix before col j0

    if (isf32) {
        float4 ov[4];
#pragma unroll
        for (int e = 0; e < 16; ++e) {
            float p = total - run;                // inclusive suffix sum at col j0+e
            run += g[e];
            p = fminf(fmaxf(p, 0.f), 63.f);
            float pf = floorf(p);
            int ipf = (int)pf;
            float a = li[wid][ipf], b = li[wid][ipf + 1];
            float o = fmaf(p - pf, b - a, a);
            reinterpret_cast<float*>(ov)[e] = o;
        }
        float4* o4 = reinterpret_cast<float4*>(outv) + (size_t)r * 256 + lane * 4;
#pragma unroll
        for (int k = 0; k < 4; ++k) o4[k] = ov[k];
    } else {
        unsigned int ov[8];
#pragma unroll
        for (int e = 0; e < 8; ++e) {
            float p0 = total - run; run += g[2 * e];
            p0 = fminf(fmaxf(p0, 0.f), 63.f);
            float pf0 = floorf(p0);
            int ip0 = (int)pf0;
            float a0 = li[wid][ip0], b0 = li[wid][ip0 + 1];
            float o0 = fmaf(p0 - pf0, b0 - a0, a0);

            float p1 = total - run; run += g[2 * e + 1];
            p1 = fminf(fmaxf(p1, 0.f), 63.f);
            float pf1 = floorf(p1);
            int ip1 = (int)pf1;
            float a1 = li[wid][ip1], b1 = li[wid][ip1 + 1];
            float o1 = fmaf(p1 - pf1, b1 - a1, a1);

            ov[e] = (unsigned)f2bf(o0) | ((unsigned)f2bf(o1) << 16);
        }
        uint4* o8 = reinterpret_cast<uint4*>(outv) + (size_t)r * 128 + lane * 2;
        o8[0] = make_uint4(ov[0], ov[1], ov[2], ov[3]);
        o8[1] = make_uint4(ov[4], ov[5], ov[6], ov[7]);
    }
}

// ---------------------------------------------------------------------------
// Fallback (ws too small): round-2 fused kernel, known-passing.
// ---------------------------------------------------------------------------
__global__ __launch_bounds__(256) void cope_fused(
    const void* __restrict__ qv, const void* __restrict__ attnv,
    const void* __restrict__ pev, void* __restrict__ outv,
    const int* __restrict__ flag)
{
    const int r = blockIdx.x;
    const int i = r & 1023;
    const int tid = threadIdx.x;
    const int lane = tid & 63;
    const int wid = tid >> 6;
    const bool isf32 = (*flag != 0);

    __shared__ float pe_f[64 * 64];
    __shared__ float q_s[64];
    __shared__ float li[64];
    __shared__ float wsum[4];

    float g[4];
    if (isf32) {
        const float4* pe4 = reinterpret_cast<const float4*>(pev);
#pragma unroll
        for (int it = 0; it < 4; ++it)
            reinterpret_cast<float4*>(pe_f)[it * 256 + tid] = pe4[it * 256 + tid];
        if (tid < 16) {
            float4 v = reinterpret_cast<const float4*>(qv)[(size_t)r * 16 + tid];
            q_s[tid * 4 + 0] = v.x; q_s[tid * 4 + 1] = v.y;
            q_s[tid * 4 + 2] = v.z; q_s[tid * 4 + 3] = v.w;
        }
        float4 av = reinterpret_cast<const float4*>(attnv)[(size_t)r * 256 + tid];
        g[0] = sigmoid_fast(av.x); g[1] = sigmoid_fast(av.y);
        g[2] = sigmoid_fast(av.z); g[3] = sigmoid_fast(av.w);
    } else {
        const uint4* pe16 = reinterpret_cast<const uint4*>(pev);
#pragma unroll
        for (int it = 0; it < 2; ++it) {
            int idx = it * 256 + tid;
            uint4 v = pe16[idx];
            float4 a, b;
            a.x = bf2f_lo(v.x); a.y = bf2f_hi(v.x);
            a.z = bf2f_lo(v.y); a.w = bf2f_hi(v.y);
            b.x = bf2f_lo(v.z); b.y = bf2f_hi(v.z);
            b.z = bf2f_lo(v.w); b.w = bf2f_hi(v.w);
            float4* dst = reinterpret_cast<float4*>(&pe_f[idx * 8]);
            dst[0] = a; dst[1] = b;
        }
        if (tid < 16) {
            ushort4 v = reinterpret_cast<const ushort4*>(qv)[(size_t)r * 16 + tid];
            q_s[tid * 4 + 0] = bf2f(v.x); q_s[tid * 4 + 1] = bf2f(v.y);
            q_s[tid * 4 + 2] = bf2f(v.z); q_s[tid * 4 + 3] = bf2f(v.w);
        }
        ushort4 av = reinterpret_cast<const ushort4*>(attnv)[(size_t)r * 256 + tid];
        g[0] = sigmoid_fast(bf2f(av.x)); g[1] = sigmoid_fast(bf2f(av.y));
        g[2] = sigmoid_fast(bf2f(av.z)); g[3] = sigmoid_fast(bf2f(av.w));
    }

    const int j0 = tid * 4;
    if (i >= j0 && i < j0 + 4) g[i - j0] = 0.f;
    float ts = g[0] + g[1] + g[2] + g[3];
    float x = ts;
#pragma unroll
    for (int s = 1; s < 64; s <<= 1) {
        float y = __shfl_up(x, s, 64);
        if (lane >= s) x += y;
    }
    if (lane == 63) wsum[wid] = x;
    __syncthreads();
    if (tid < 64) {
        float acc = 0.f;
#pragma unroll
        for (int d = 0; d < 64; ++d) acc += q_s[d] * pe_f[d * 64 + tid];
        li[tid] = acc;
    }
    const float s0 = wsum[0], s1 = wsum[1], s2 = wsum[2], s3 = wsum[3];
    const float total = s0 + s1 + s2 + s3;
    float woff = 0.f;
    if (wid > 0) woff += s0;
    if (wid > 1) woff += s1;
    if (wid > 2) woff += s2;
    float run = woff + (x - ts);
    __syncthreads();

    float o[4];
#pragma unroll
    for (int e = 0; e < 4; ++e) {
        float p = total - run;
        run += g[e];
        p = fminf(fmaxf(p, 0.f), 63.f);
        float pf = floorf(p);
        int ipf = (int)pf;
        int ipc = min(ipf + 1, 63);
        float w = p - pf;
        o[e] = li[ipf] + w * (li[ipc] - li[ipf]);
    }
    if (isf32) {
        float4 ov; ov.x = o[0]; ov.y = o[1]; ov.z = o[2]; ov.w = o[3];
        reinterpret_cast<float4*>(outv)[(size_t)r * 256 + tid] = ov;
    } else {
        ushort4 ov;
        ov.x = f2bf(o[0]); ov.y = f2bf(o[1]); ov.z = f2bf(o[2]); ov.w = f2bf(o[3]);
        reinterpret_cast<ushort4*>(outv)[(size_t)r * 256 + tid] = ov;
    }
}

extern "C" void kernel_launch(void* const* d_in, const int* in_sizes, int n_in,
                              void* d_out, int out_size, void* d_ws, size_t ws_size,
                              hipStream_t stream) {
    const void* q    = d_in[0];
    const void* attn = d_in[1];
    const void* pe   = d_in[2];
    int* flag = (int*)d_ws;
    float* li = (float*)((char*)d_ws + 256);

    const long L = 1024;
    const long rows = (long)in_sizes[1] / L;   // 49152
    const size_t ws_need = 256 + (size_t)rows * 64 * sizeof(float);

    cope_detect<<<1, 256, 0, stream>>>((const unsigned short*)d_in[0], flag);
    if (ws_size >= ws_need) {
        cope_li<<<(int)(rows / 64), 256, 0, stream>>>(q, pe, li, flag);
        cope_row4<<<(int)((rows + 3) / 4), 256, 0, stream>>>(attn, li, d_out, flag, (int)rows);
    } else {
        cope_fused<<<(int)rows, 256, 0, stream>>>(q, attn, pe, d_out, flag);
    }
}

// Round 2
// 338.546 us; speedup vs baseline: 1.0586x; 1.0586x over previous
//
#include <hip/hip_runtime.h>
#include <hip/hip_bf16.h>

// CoPE, bf16 I/O (device-detected; f32 path kept). dur_us carries ~234us of
// harness fill/restore floor; our budget is the kernels themselves.
//
// Round-2 lesson (this session): wave-per-row k2 (16 cols/lane) REGRESSED
// +18.6us — thin threads (4 cols/thread, 196k waves) win on TLP/latency
// hiding. k2 shape is locked to the proven 1-block-per-row form.
//
// This round: detect kernel folded into k1 (each k1 block re-detects from the
// SAME first 1KB of q — identical verdict everywhere, L2-broadcast-hot; block
// 0 publishes the flag for k2). Hot path is now 2 kernels instead of 3,
// saving one serial launch + grid drain.
//
// k1 (cope_li): li[rows][64] f32 = q @ pos_emb into d_ws (amortizes pos_emb
//   staging over 64 rows). Inline dtype detect at block start.
// k2 (cope_row): proven thin-thread shape: 1 block = 1 row, 256 thr,
//   4 cols/thread, li row from ws in tiny LDS, ONE barrier, scalar ds_read
//   gathers over 65-word padded row.

__device__ __forceinline__ float bf2f(unsigned short u) {
    union { unsigned int i; float f; } t; t.i = ((unsigned int)u) << 16; return t.f;
}
__device__ __forceinline__ float bf2f_lo(unsigned int v) {
    union { unsigned int i; float f; } t; t.i = v << 16; return t.f;
}
__device__ __forceinline__ float bf2f_hi(unsigned int v) {
    union { unsigned int i; float f; } t; t.i = v & 0xffff0000u; return t.f;
}
__device__ __forceinline__ unsigned short f2bf(float f) {
    union { float f; unsigned int i; } t; t.f = f;
    unsigned int lsb = (t.i >> 16) & 1u;
    t.i += 0x7fffu + lsb;
    return (unsigned short)(t.i >> 16);
}
__device__ __forceinline__ float sigmoid_fast(float x) {
    float e = __builtin_amdgcn_exp2f(-1.44269504f * x);
    return __builtin_amdgcn_rcpf(1.0f + e);
}

// Standalone detect — only used on the fallback (ws too small) path.
__global__ __launch_bounds__(256) void cope_detect(
    const unsigned short* __restrict__ q, int* __restrict__ flag)
{
    const int tid = threadIdx.x;
    unsigned short u = q[2 * tid];
    int e = (u >> 7) & 0xFF;
    unsigned long long m = __ballot(e >= 200);
    __shared__ int cnt;
    if (tid == 0) cnt = 0;
    __syncthreads();
    if ((tid & 63) == 0) atomicAdd(&cnt, __popcll(m));
    __syncthreads();
    if (tid == 0) *flag = (cnt > 8) ? 1 : 0;   // 1 => float32 buffers
}

// ---------------------------------------------------------------------------
// k1: li[r][n] = sum_d q[r][d] * pe[d][n].  64 rows/block, 256 thr, 4x4 tile.
// Detects dtype inline (same 1KB of q in every block -> consistent verdict);
// block 0 publishes flag for k2.
// ---------------------------------------------------------------------------
__global__ __launch_bounds__(256) void cope_li(
    const void* __restrict__ qv, const void* __restrict__ pev,
    float* __restrict__ li, int* __restrict__ flag)
{
    __shared__ float pe_f[64 * 64];   // [d][n]
    __shared__ float q_t[64 * 64];    // [d][r_local]
    __shared__ int cnt;
    const int tid = threadIdx.x;

    // Inline dtype detect: all blocks read the SAME first 1KB of q, so every
    // block reaches the same verdict. Region is L2-hot after the first block.
    {
        unsigned short u = reinterpret_cast<const unsigned short*>(qv)[2 * tid];
        int e = (u >> 7) & 0xFF;
        unsigned long long m = __ballot(e >= 200);
        if (tid == 0) cnt = 0;
        __syncthreads();
        if ((tid & 63) == 0) atomicAdd(&cnt, __popcll(m));
        __syncthreads();
    }
    const bool isf32 = (cnt > 8);
    if (blockIdx.x == 0 && tid == 0) *flag = isf32 ? 1 : 0;   // for k2

    if (isf32) {
        const float4* pe4 = reinterpret_cast<const float4*>(pev);
#pragma unroll
        for (int it = 0; it < 4; ++it)
            reinterpret_cast<float4*>(pe_f)[it * 256 + tid] = pe4[it * 256 + tid];
        const float4* q4 = reinterpret_cast<const float4*>(qv) + (size_t)blockIdx.x * 1024;
#pragma unroll
        for (int it = 0; it < 4; ++it) {
            int idx = it * 256 + tid;
            int d4 = idx >> 6, rr = idx & 63;
            float4 v = q4[rr * 16 + d4];
            q_t[(d4 * 4 + 0) * 64 + rr] = v.x;
            q_t[(d4 * 4 + 1) * 64 + rr] = v.y;
            q_t[(d4 * 4 + 2) * 64 + rr] = v.z;
            q_t[(d4 * 4 + 3) * 64 + rr] = v.w;
        }
    } else {
        const uint4* pe16 = reinterpret_cast<const uint4*>(pev);
#pragma unroll
        for (int it = 0; it < 2; ++it) {
            int idx = it * 256 + tid;       // 512 uint4 = 4096 bf16
            uint4 v = pe16[idx];
            float4 a, b;
            a.x = bf2f_lo(v.x); a.y = bf2f_hi(v.x);
            a.z = bf2f_lo(v.y); a.w = bf2f_hi(v.y);
            b.x = bf2f_lo(v.z); b.y = bf2f_hi(v.z);
            b.z = bf2f_lo(v.w); b.w = bf2f_hi(v.w);
            float4* dst = reinterpret_cast<float4*>(&pe_f[idx * 8]);
            dst[0] = a; dst[1] = b;
        }
        const ushort4* q4 = reinterpret_cast<const ushort4*>(qv) + (size_t)blockIdx.x * 1024;
#pragma unroll
        for (int it = 0; it < 4; ++it) {
            int idx = it * 256 + tid;
            int d4 = idx >> 6, rr = idx & 63;
            ushort4 v = q4[rr * 16 + d4];
            q_t[(d4 * 4 + 0) * 64 + rr] = bf2f(v.x);
            q_t[(d4 * 4 + 1) * 64 + rr] = bf2f(v.y);
            q_t[(d4 * 4 + 2) * 64 + rr] = bf2f(v.z);
            q_t[(d4 * 4 + 3) * 64 + rr] = bf2f(v.w);
        }
    }
    __syncthreads();

    const int r0 = (tid & 15) * 4, n0 = (tid >> 4) * 4;
    float acc[4][4];
#pragma unroll
    for (int a = 0; a < 4; ++a)
#pragma unroll
        for (int b = 0; b < 4; ++b) acc[a][b] = 0.f;

#pragma unroll 8
    for (int d = 0; d < 64; ++d) {
        float4 qv4 = *reinterpret_cast<const float4*>(&q_t[d * 64 + r0]);
        float4 pv = *reinterpret_cast<const float4*>(&pe_f[d * 64 + n0]);
        acc[0][0] += qv4.x * pv.x; acc[0][1] += qv4.x * pv.y; acc[0][2] += qv4.x * pv.z; acc[0][3] += qv4.x * pv.w;
        acc[1][0] += qv4.y * pv.x; acc[1][1] += qv4.y * pv.y; acc[1][2] += qv4.y * pv.z; acc[1][3] += qv4.y * pv.w;
        acc[2][0] += qv4.z * pv.x; acc[2][1] += qv4.z * pv.y; acc[2][2] += qv4.z * pv.z; acc[2][3] += qv4.z * pv.w;
        acc[3][0] += qv4.w * pv.x; acc[3][1] += qv4.w * pv.y; acc[3][2] += qv4.w * pv.z; acc[3][3] += qv4.w * pv.w;
    }
#pragma unroll
    for (int a = 0; a < 4; ++a) {
        size_t row = (size_t)blockIdx.x * 64 + r0 + a;
        float4 o; o.x = acc[a][0]; o.y = acc[a][1]; o.z = acc[a][2]; o.w = acc[a][3];
        *reinterpret_cast<float4*>(&li[row * 64 + n0]) = o;
    }
}

// ---------------------------------------------------------------------------
// k2: 1 block = 1 row, 256 threads x 4 columns. One barrier. Tiny LDS.
// (Proven shape — do not widen per-thread work; round-2 of this session
// measured 16 cols/lane at +18.6us.)
// ---------------------------------------------------------------------------
__global__ __launch_bounds__(256) void cope_row(
    const void* __restrict__ attnv,
    const float* __restrict__ li_ws,
    void* __restrict__ outv,
    const int* __restrict__ flag)
{
    const int r = blockIdx.x;               // 49152 rows
    const int i = r & 1023;                 // diagonal column
    const int tid = threadIdx.x;
    const int lane = tid & 63;
    const int wid = tid >> 6;
    const bool isf32 = (*flag != 0);

    __shared__ float li[65];                // 64 + pad (li[64]=li[63], w==0 there)
    __shared__ float wsum[4];

    if (tid < 64) {
        float lv = li_ws[(size_t)r * 64 + tid];
        li[tid] = lv;
        if (tid == 63) li[64] = lv;
    }

    float g[4];
    if (isf32) {
        float4 av = reinterpret_cast<const float4*>(attnv)[(size_t)r * 256 + tid];
        g[0] = sigmoid_fast(av.x); g[1] = sigmoid_fast(av.y);
        g[2] = sigmoid_fast(av.z); g[3] = sigmoid_fast(av.w);
    } else {
        ushort4 av = reinterpret_cast<const ushort4*>(attnv)[(size_t)r * 256 + tid];
        g[0] = sigmoid_fast(bf2f(av.x)); g[1] = sigmoid_fast(bf2f(av.y));
        g[2] = sigmoid_fast(bf2f(av.z)); g[3] = sigmoid_fast(bf2f(av.w));
    }

    const int j0 = tid * 4;
    if (i >= j0 && i < j0 + 4) g[i - j0] = 0.f;   // zero diagonal

    float ts = g[0] + g[1] + g[2] + g[3];

    // wave-inclusive scan of per-thread sums
    float x = ts;
#pragma unroll
    for (int s = 1; s < 64; s <<= 1) {
        float y = __shfl_up(x, s, 64);
        if (lane >= s) x += y;
    }
    if (lane == 63) wsum[wid] = x;

    __syncthreads();                        // li + wsum visible

    const float s0 = wsum[0], s1 = wsum[1], s2 = wsum[2], s3 = wsum[3];
    const float total = s0 + s1 + s2 + s3;
    float woff = 0.f;
    if (wid > 0) woff += s0;
    if (wid > 1) woff += s1;
    if (wid > 2) woff += s2;
    float run = woff + (x - ts);            // exclusive prefix before col j0

    float o[4];
#pragma unroll
    for (int e = 0; e < 4; ++e) {
        float p = total - run;              // inclusive suffix sum at j0+e
        run += g[e];
        p = fminf(fmaxf(p, 0.f), 63.f);
        float pf = floorf(p);
        int ipf = (int)pf;
        float a = li[ipf], b = li[ipf + 1];
        o[e] = fmaf(p - pf, b - a, a);
    }

    if (isf32) {
        float4 ov; ov.x = o[0]; ov.y = o[1]; ov.z = o[2]; ov.w = o[3];
        reinterpret_cast<float4*>(outv)[(size_t)r * 256 + tid] = ov;
    } else {
        uint2 ov;
        ov.x = (unsigned)f2bf(o[0]) | ((unsigned)f2bf(o[1]) << 16);
        ov.y = (unsigned)f2bf(o[2]) | ((unsigned)f2bf(o[3]) << 16);
        reinterpret_cast<uint2*>(outv)[(size_t)r * 256 + tid] = ov;
    }
}

// ---------------------------------------------------------------------------
// Fallback (ws too small): round-2 fused kernel, known-passing.
// ---------------------------------------------------------------------------
__global__ __launch_bounds__(256) void cope_fused(
    const void* __restrict__ qv, const void* __restrict__ attnv,
    const void* __restrict__ pev, void* __restrict__ outv,
    const int* __restrict__ flag)
{
    const int r = blockIdx.x;
    const int i = r & 1023;
    const int tid = threadIdx.x;
    const int lane = tid & 63;
    const int wid = tid >> 6;
    const bool isf32 = (*flag != 0);

    __shared__ float pe_f[64 * 64];
    __shared__ float q_s[64];
    __shared__ float li[64];
    __shared__ float wsum[4];

    float g[4];
    if (isf32) {
        const float4* pe4 = reinterpret_cast<const float4*>(pev);
#pragma unroll
        for (int it = 0; it < 4; ++it)
            reinterpret_cast<float4*>(pe_f)[it * 256 + tid] = pe4[it * 256 + tid];
        if (tid < 16) {
            float4 v = reinterpret_cast<const float4*>(qv)[(size_t)r * 16 + tid];
            q_s[tid * 4 + 0] = v.x; q_s[tid * 4 + 1] = v.y;
            q_s[tid * 4 + 2] = v.z; q_s[tid * 4 + 3] = v.w;
        }
        float4 av = reinterpret_cast<const float4*>(attnv)[(size_t)r * 256 + tid];
        g[0] = sigmoid_fast(av.x); g[1] = sigmoid_fast(av.y);
        g[2] = sigmoid_fast(av.z); g[3] = sigmoid_fast(av.w);
    } else {
        const uint4* pe16 = reinterpret_cast<const uint4*>(pev);
#pragma unroll
        for (int it = 0; it < 2; ++it) {
            int idx = it * 256 + tid;
            uint4 v = pe16[idx];
            float4 a, b;
            a.x = bf2f_lo(v.x); a.y = bf2f_hi(v.x);
            a.z = bf2f_lo(v.y); a.w = bf2f_hi(v.y);
            b.x = bf2f_lo(v.z); b.y = bf2f_hi(v.z);
            b.z = bf2f_lo(v.w); b.w = bf2f_hi(v.w);
            float4* dst = reinterpret_cast<float4*>(&pe_f[idx * 8]);
            dst[0] = a; dst[1] = b;
        }
        if (tid < 16) {
            ushort4 v = reinterpret_cast<const ushort4*>(qv)[(size_t)r * 16 + tid];
            q_s[tid * 4 + 0] = bf2f(v.x); q_s[tid * 4 + 1] = bf2f(v.y);
            q_s[tid * 4 + 2] = bf2f(v.z); q_s[tid * 4 + 3] = bf2f(v.w);
        }
        ushort4 av = reinterpret_cast<const ushort4*>(attnv)[(size_t)r * 256 + tid];
        g[0] = sigmoid_fast(bf2f(av.x)); g[1] = sigmoid_fast(bf2f(av.y));
        g[2] = sigmoid_fast(bf2f(av.z)); g[3] = sigmoid_fast(bf2f(av.w));
    }

    const int j0 = tid * 4;
    if (i >= j0 && i < j0 + 4) g[i - j0] = 0.f;
    float ts = g[0] + g[1] + g[2] + g[3];
    float x = ts;
#pragma unroll
    for (int s = 1; s < 64; s <<= 1) {
        float y = __shfl_up(x, s, 64);
        if (lane >= s) x += y;
    }
    if (lane == 63) wsum[wid] = x;
    __syncthreads();
    if (tid < 64) {
        float acc = 0.f;
#pragma unroll
        for (int d = 0; d < 64; ++d) acc += q_s[d] * pe_f[d * 64 + tid];
        li[tid] = acc;
    }
    const float s0 = wsum[0], s1 = wsum[1], s2 = wsum[2], s3 = wsum[3];
    const float total = s0 + s1 + s2 + s3;
    float woff = 0.f;
    if (wid > 0) woff += s0;
    if (wid > 1) woff += s1;
    if (wid > 2) woff += s2;
    float run = woff + (x - ts);
    __syncthreads();

    float o[4];
#pragma unroll
    for (int e = 0; e < 4; ++e) {
        float p = total - run;
        run += g[e];
        p = fminf(fmaxf(p, 0.f), 63.f);
        float pf = floorf(p);
        int ipf = (int)pf;
        int ipc = min(ipf + 1, 63);
        float w = p - pf;
        o[e] = li[ipf] + w * (li[ipc] - li[ipf]);
    }
    if (isf32) {
        float4 ov; ov.x = o[0]; ov.y = o[1]; ov.z = o[2]; ov.w = o[3];
        reinterpret_cast<float4*>(outv)[(size_t)r * 256 + tid] = ov;
    } else {
        ushort4 ov;
        ov.x = f2bf(o[0]); ov.y = f2bf(o[1]); ov.z = f2bf(o[2]); ov.w = f2bf(o[3]);
        reinterpret_cast<ushort4*>(outv)[(size_t)r * 256 + tid] = ov;
    }
}

extern "C" void kernel_launch(void* const* d_in, const int* in_sizes, int n_in,
                              void* d_out, int out_size, void* d_ws, size_t ws_size,
                              hipStream_t stream) {
    const void* q    = d_in[0];
    const void* attn = d_in[1];
    const void* pe   = d_in[2];
    int* flag = (int*)d_ws;
    float* li = (float*)((char*)d_ws + 256);

    const long L = 1024;
    const long rows = (long)in_sizes[1] / L;   // 49152
    const size_t ws_need = 256 + (size_t)rows * 64 * sizeof(float);

    if (ws_size >= ws_need) {
        // detect folded into k1; k1 block 0 publishes flag for k2
        cope_li<<<(int)(rows / 64), 256, 0, stream>>>(q, pe, li, flag);
        cope_row<<<(int)rows, 256, 0, stream>>>(attn, li, d_out, flag);
    } else {
        cope_detect<<<1, 256, 0, stream>>>((const unsigned short*)d_in[0], flag);
        cope_fused<<<(int)rows, 256, 0, stream>>>(q, attn, pe, d_out, flag);
    }
}

// Round 5
// 336.710 us; speedup vs baseline: 1.0644x; 1.0055x over previous
//
#include <hip/hip_runtime.h>
#include <hip/hip_bf16.h>

// CoPE, bf16 I/O (device-detected; f32 path kept). dur_us carries ~234us of
// harness fill/restore floor; our budget is the kernels themselves (~104us).
//
// Session lessons:
//  - R1: wave-per-row k2 (16 cols/lane) REGRESSED +18.6us — thin threads
//    (4 cols/thread, 196k waves) win on TLP. k2 shape locked.
//  - R2: detect folded into k1: -1.3us. Launch overhead ~1-3us/kernel.
//  - R3: __builtin_amdgcn_update_dpp args MUST be literal constants ->
//    template parameters, not function args.
//  - R4: infra failure (container), kernel untested — resubmitted verbatim.
//
// This round (k2 only):
//  - DPP wave64 scan (row_shr 1/2/4/8 + row_bcast 15/31) replaces the
//    shfl_up scan: 6 ds_bpermute -> 0 DS ops (DS is per-CU; est 27us -> ~8us).
//  - Clamp fast path: p=min(suffix,63); suffix is monotone decreasing, so a
//    wave whose LAST element still has p>=63 writes li[63] for its whole
//    256-col span (w==0 exactly). Wave-uniform __all() branch skips 8 gather
//    DS ops + ~48 interp VALU ops on the ~87% saturated columns of this
//    data distribution. Correct for any data (worst case = slow path).

__device__ __forceinline__ float bf2f(unsigned short u) {
    union { unsigned int i; float f; } t; t.i = ((unsigned int)u) << 16; return t.f;
}
__device__ __forceinline__ float bf2f_lo(unsigned int v) {
    union { unsigned int i; float f; } t; t.i = v << 16; return t.f;
}
__device__ __forceinline__ float bf2f_hi(unsigned int v) {
    union { unsigned int i; float f; } t; t.i = v & 0xffff0000u; return t.f;
}
__device__ __forceinline__ unsigned short f2bf(float f) {
    union { float f; unsigned int i; } t; t.f = f;
    unsigned int lsb = (t.i >> 16) & 1u;
    t.i += 0x7fffu + lsb;
    return (unsigned short)(t.i >> 16);
}
__device__ __forceinline__ float sigmoid_fast(float x) {
    float e = __builtin_amdgcn_exp2f(-1.44269504f * x);
    return __builtin_amdgcn_rcpf(1.0f + e);
}

// DPP helper: x + shifted(x). Control words are TEMPLATE constants (the
// builtin requires literal constant args — R3 compile failure). bound_ctrl=1
// gives 0 for out-of-range sources; masked-out rows get old=0 (unchanged add).
template <int CTRL, int ROW_MASK>
__device__ __forceinline__ float dpp_add(float x) {
    int s = __builtin_amdgcn_update_dpp(0, __float_as_int(x), CTRL, ROW_MASK, 0xf, true);
    return x + __int_as_float(s);
}
// Inclusive add-scan across 64 lanes, all on the VALU pipe (no DS ops).
__device__ __forceinline__ float wave_incl_scan(float x) {
    x = dpp_add<0x111, 0xf>(x);   // row_shr:1
    x = dpp_add<0x112, 0xf>(x);   // row_shr:2
    x = dpp_add<0x114, 0xf>(x);   // row_shr:4
    x = dpp_add<0x118, 0xf>(x);   // row_shr:8  -> scan within 16-lane rows
    x = dpp_add<0x142, 0xa>(x);   // row_bcast:15 -> rows 1,3
    x = dpp_add<0x143, 0xc>(x);   // row_bcast:31 -> rows 2,3
    return x;
}

// Standalone detect — only used on the fallback (ws too small) path.
__global__ __launch_bounds__(256) void cope_detect(
    const unsigned short* __restrict__ q, int* __restrict__ flag)
{
    const int tid = threadIdx.x;
    unsigned short u = q[2 * tid];
    int e = (u >> 7) & 0xFF;
    unsigned long long m = __ballot(e >= 200);
    __shared__ int cnt;
    if (tid == 0) cnt = 0;
    __syncthreads();
    if ((tid & 63) == 0) atomicAdd(&cnt, __popcll(m));
    __syncthreads();
    if (tid == 0) *flag = (cnt > 8) ? 1 : 0;   // 1 => float32 buffers
}

// ---------------------------------------------------------------------------
// k1: li[r][n] = sum_d q[r][d] * pe[d][n].  64 rows/block, 256 thr, 4x4 tile.
// Detects dtype inline (same 1KB of q in every block -> consistent verdict);
// block 0 publishes flag for k2.
// ---------------------------------------------------------------------------
__global__ __launch_bounds__(256) void cope_li(
    const void* __restrict__ qv, const void* __restrict__ pev,
    float* __restrict__ li, int* __restrict__ flag)
{
    __shared__ float pe_f[64 * 64];   // [d][n]
    __shared__ float q_t[64 * 64];    // [d][r_local]
    __shared__ int cnt;
    const int tid = threadIdx.x;

    {
        unsigned short u = reinterpret_cast<const unsigned short*>(qv)[2 * tid];
        int e = (u >> 7) & 0xFF;
        unsigned long long m = __ballot(e >= 200);
        if (tid == 0) cnt = 0;
        __syncthreads();
        if ((tid & 63) == 0) atomicAdd(&cnt, __popcll(m));
        __syncthreads();
    }
    const bool isf32 = (cnt > 8);
    if (blockIdx.x == 0 && tid == 0) *flag = isf32 ? 1 : 0;   // for k2

    if (isf32) {
        const float4* pe4 = reinterpret_cast<const float4*>(pev);
#pragma unroll
        for (int it = 0; it < 4; ++it)
            reinterpret_cast<float4*>(pe_f)[it * 256 + tid] = pe4[it * 256 + tid];
        const float4* q4 = reinterpret_cast<const float4*>(qv) + (size_t)blockIdx.x * 1024;
#pragma unroll
        for (int it = 0; it < 4; ++it) {
            int idx = it * 256 + tid;
            int d4 = idx >> 6, rr = idx & 63;
            float4 v = q4[rr * 16 + d4];
            q_t[(d4 * 4 + 0) * 64 + rr] = v.x;
            q_t[(d4 * 4 + 1) * 64 + rr] = v.y;
            q_t[(d4 * 4 + 2) * 64 + rr] = v.z;
            q_t[(d4 * 4 + 3) * 64 + rr] = v.w;
        }
    } else {
        const uint4* pe16 = reinterpret_cast<const uint4*>(pev);
#pragma unroll
        for (int it = 0; it < 2; ++it) {
            int idx = it * 256 + tid;       // 512 uint4 = 4096 bf16
            uint4 v = pe16[idx];
            float4 a, b;
            a.x = bf2f_lo(v.x); a.y = bf2f_hi(v.x);
            a.z = bf2f_lo(v.y); a.w = bf2f_hi(v.y);
            b.x = bf2f_lo(v.z); b.y = bf2f_hi(v.z);
            b.z = bf2f_lo(v.w); b.w = bf2f_hi(v.w);
            float4* dst = reinterpret_cast<float4*>(&pe_f[idx * 8]);
            dst[0] = a; dst[1] = b;
        }
        const ushort4* q4 = reinterpret_cast<const ushort4*>(qv) + (size_t)blockIdx.x * 1024;
#pragma unroll
        for (int it = 0; it < 4; ++it) {
            int idx = it * 256 + tid;
            int d4 = idx >> 6, rr = idx & 63;
            ushort4 v = q4[rr * 16 + d4];
            q_t[(d4 * 4 + 0) * 64 + rr] = bf2f(v.x);
            q_t[(d4 * 4 + 1) * 64 + rr] = bf2f(v.y);
            q_t[(d4 * 4 + 2) * 64 + rr] = bf2f(v.z);
            q_t[(d4 * 4 + 3) * 64 + rr] = bf2f(v.w);
        }
    }
    __syncthreads();

    const int r0 = (tid & 15) * 4, n0 = (tid >> 4) * 4;
    float acc[4][4];
#pragma unroll
    for (int a = 0; a < 4; ++a)
#pragma unroll
        for (int b = 0; b < 4; ++b) acc[a][b] = 0.f;

#pragma unroll 8
    for (int d = 0; d < 64; ++d) {
        float4 qv4 = *reinterpret_cast<const float4*>(&q_t[d * 64 + r0]);
        float4 pv = *reinterpret_cast<const float4*>(&pe_f[d * 64 + n0]);
        acc[0][0] += qv4.x * pv.x; acc[0][1] += qv4.x * pv.y; acc[0][2] += qv4.x * pv.z; acc[0][3] += qv4.x * pv.w;
        acc[1][0] += qv4.y * pv.x; acc[1][1] += qv4.y * pv.y; acc[1][2] += qv4.y * pv.z; acc[1][3] += qv4.y * pv.w;
        acc[2][0] += qv4.z * pv.x; acc[2][1] += qv4.z * pv.y; acc[2][2] += qv4.z * pv.z; acc[2][3] += qv4.z * pv.w;
        acc[3][0] += qv4.w * pv.x; acc[3][1] += qv4.w * pv.y; acc[3][2] += qv4.w * pv.z; acc[3][3] += qv4.w * pv.w;
    }
#pragma unroll
    for (int a = 0; a < 4; ++a) {
        size_t row = (size_t)blockIdx.x * 64 + r0 + a;
        float4 o; o.x = acc[a][0]; o.y = acc[a][1]; o.z = acc[a][2]; o.w = acc[a][3];
        *reinterpret_cast<float4*>(&li[row * 64 + n0]) = o;
    }
}

// ---------------------------------------------------------------------------
// k2: 1 block = 1 row, 256 threads x 4 columns. One barrier. Tiny LDS.
// (Proven shape — do not widen per-thread work; R1 measured 16 cols/lane
// at +18.6us.) DPP scan + clamp fast path this round.
// ---------------------------------------------------------------------------
__global__ __launch_bounds__(256) void cope_row(
    const void* __restrict__ attnv,
    const float* __restrict__ li_ws,
    void* __restrict__ outv,
    const int* __restrict__ flag)
{
    const int r = blockIdx.x;               // 49152 rows
    const int i = r & 1023;                 // diagonal column
    const int tid = threadIdx.x;
    const int lane = tid & 63;
    const int wid = tid >> 6;
    const bool isf32 = (*flag != 0);

    __shared__ float li[65];                // 64 + pad (li[64]=li[63], w==0 there)
    __shared__ float wsum[4];

    if (tid < 64) {
        float lv = li_ws[(size_t)r * 64 + tid];
        li[tid] = lv;
        if (tid == 63) li[64] = lv;
    }

    float g[4];
    if (isf32) {
        float4 av = reinterpret_cast<const float4*>(attnv)[(size_t)r * 256 + tid];
        g[0] = sigmoid_fast(av.x); g[1] = sigmoid_fast(av.y);
        g[2] = sigmoid_fast(av.z); g[3] = sigmoid_fast(av.w);
    } else {
        ushort4 av = reinterpret_cast<const ushort4*>(attnv)[(size_t)r * 256 + tid];
        g[0] = sigmoid_fast(bf2f(av.x)); g[1] = sigmoid_fast(bf2f(av.y));
        g[2] = sigmoid_fast(bf2f(av.z)); g[3] = sigmoid_fast(bf2f(av.w));
    }

    const int j0 = tid * 4;
    if (i >= j0 && i < j0 + 4) g[i - j0] = 0.f;   // zero diagonal

    float ts = g[0] + g[1] + g[2] + g[3];

    // wave-inclusive scan of per-thread sums — DPP, zero DS-pipe ops
    float x = wave_incl_scan(ts);
    if (lane == 63) wsum[wid] = x;

    __syncthreads();                        // li + wsum visible

    const float s0 = wsum[0], s1 = wsum[1], s2 = wsum[2], s3 = wsum[3];
    const float total = s0 + s1 + s2 + s3;
    float woff = 0.f;
    if (wid > 0) woff += s0;
    if (wid > 1) woff += s1;
    if (wid > 2) woff += s2;
    float run = woff + (x - ts);            // exclusive prefix before col j0

    // Fast path: suffix sums are monotone decreasing; if this thread's LAST
    // element still has p >= 63, all 4 of its outputs are exactly li[63]
    // (p clamps to 63, w == 0). Wave-uniform branch over the wave's span.
    const float p_last = total - (run + ts - g[3]);
    if (__all(p_last >= 63.f)) {
        const float c = li[63];
        if (isf32) {
            float4 ov; ov.x = c; ov.y = c; ov.z = c; ov.w = c;
            reinterpret_cast<float4*>(outv)[(size_t)r * 256 + tid] = ov;
        } else {
            unsigned cb = (unsigned)f2bf(c);
            cb |= cb << 16;
            uint2 ov; ov.x = cb; ov.y = cb;
            reinterpret_cast<uint2*>(outv)[(size_t)r * 256 + tid] = ov;
        }
        return;
    }

    float o[4];
#pragma unroll
    for (int e = 0; e < 4; ++e) {
        float p = total - run;              // inclusive suffix sum at j0+e
        run += g[e];
        p = fminf(fmaxf(p, 0.f), 63.f);
        float pf = floorf(p);
        int ipf = (int)pf;
        float a = li[ipf], b = li[ipf + 1];
        o[e] = fmaf(p - pf, b - a, a);
    }

    if (isf32) {
        float4 ov; ov.x = o[0]; ov.y = o[1]; ov.z = o[2]; ov.w = o[3];
        reinterpret_cast<float4*>(outv)[(size_t)r * 256 + tid] = ov;
    } else {
        uint2 ov;
        ov.x = (unsigned)f2bf(o[0]) | ((unsigned)f2bf(o[1]) << 16);
        ov.y = (unsigned)f2bf(o[2]) | ((unsigned)f2bf(o[3]) << 16);
        reinterpret_cast<uint2*>(outv)[(size_t)r * 256 + tid] = ov;
    }
}

// ---------------------------------------------------------------------------
// Fallback (ws too small): round-2 fused kernel, known-passing.
// ---------------------------------------------------------------------------
__global__ __launch_bounds__(256) void cope_fused(
    const void* __restrict__ qv, const void* __restrict__ attnv,
    const void* __restrict__ pev, void* __restrict__ outv,
    const int* __restrict__ flag)
{
    const int r = blockIdx.x;
    const int i = r & 1023;
    const int tid = threadIdx.x;
    const int lane = tid & 63;
    const int wid = tid >> 6;
    const bool isf32 = (*flag != 0);

    __shared__ float pe_f[64 * 64];
    __shared__ float q_s[64];
    __shared__ float li[64];
    __shared__ float wsum[4];

    float g[4];
    if (isf32) {
        const float4* pe4 = reinterpret_cast<const float4*>(pev);
#pragma unroll
        for (int it = 0; it < 4; ++it)
            reinterpret_cast<float4*>(pe_f)[it * 256 + tid] = pe4[it * 256 + tid];
        if (tid < 16) {
            float4 v = reinterpret_cast<const float4*>(qv)[(size_t)r * 16 + tid];
            q_s[tid * 4 + 0] = v.x; q_s[tid * 4 + 1] = v.y;
            q_s[tid * 4 + 2] = v.z; q_s[tid * 4 + 3] = v.w;
        }
        float4 av = reinterpret_cast<const float4*>(attnv)[(size_t)r * 256 + tid];
        g[0] = sigmoid_fast(av.x); g[1] = sigmoid_fast(av.y);
        g[2] = sigmoid_fast(av.z); g[3] = sigmoid_fast(av.w);
    } else {
        const uint4* pe16 = reinterpret_cast<const uint4*>(pev);
#pragma unroll
        for (int it = 0; it < 2; ++it) {
            int idx = it * 256 + tid;
            uint4 v = pe16[idx];
            float4 a, b;
            a.x = bf2f_lo(v.x); a.y = bf2f_hi(v.x);
            a.z = bf2f_lo(v.y); a.w = bf2f_hi(v.y);
            b.x = bf2f_lo(v.z); b.y = bf2f_hi(v.z);
            b.z = bf2f_lo(v.w); b.w = bf2f_hi(v.w);
            float4* dst = reinterpret_cast<float4*>(&pe_f[idx * 8]);
            dst[0] = a; dst[1] = b;
        }
        if (tid < 16) {
            ushort4 v = reinterpret_cast<const ushort4*>(qv)[(size_t)r * 16 + tid];
            q_s[tid * 4 + 0] = bf2f(v.x); q_s[tid * 4 + 1] = bf2f(v.y);
            q_s[tid * 4 + 2] = bf2f(v.z); q_s[tid * 4 + 3] = bf2f(v.w);
        }
        ushort4 av = reinterpret_cast<const ushort4*>(attnv)[(size_t)r * 256 + tid];
        g[0] = sigmoid_fast(bf2f(av.x)); g[1] = sigmoid_fast(bf2f(av.y));
        g[2] = sigmoid_fast(bf2f(av.z)); g[3] = sigmoid_fast(bf2f(av.w));
    }

    const int j0 = tid * 4;
    if (i >= j0 && i < j0 + 4) g[i - j0] = 0.f;
    float ts = g[0] + g[1] + g[2] + g[3];
    float x = ts;
#pragma unroll
    for (int s = 1; s < 64; s <<= 1) {
        float y = __shfl_up(x, s, 64);
        if (lane >= s) x += y;
    }
    if (lane == 63) wsum[wid] = x;
    __syncthreads();
    if (tid < 64) {
        float acc = 0.f;
#pragma unroll
        for (int d = 0; d < 64; ++d) acc += q_s[d] * pe_f[d * 64 + tid];
        li[tid] = acc;
    }
    const float s0 = wsum[0], s1 = wsum[1], s2 = wsum[2], s3 = wsum[3];
    const float total = s0 + s1 + s2 + s3;
    float woff = 0.f;
    if (wid > 0) woff += s0;
    if (wid > 1) woff += s1;
    if (wid > 2) woff += s2;
    float run = woff + (x - ts);
    __syncthreads();

    float o[4];
#pragma unroll
    for (int e = 0; e < 4; ++e) {
        float p = total - run;
        run += g[e];
        p = fminf(fmaxf(p, 0.f), 63.f);
        float pf = floorf(p);
        int ipf = (int)pf;
        int ipc = min(ipf + 1, 63);
        float w = p - pf;
        o[e] = li[ipf] + w * (li[ipc] - li[ipf]);
    }
    if (isf32) {
        float4 ov; ov.x = o[0]; ov.y = o[1]; ov.z = o[2]; ov.w = o[3];
        reinterpret_cast<float4*>(outv)[(size_t)r * 256 + tid] = ov;
    } else {
        ushort4 ov;
        ov.x = f2bf(o[0]); ov.y = f2bf(o[1]); ov.z = f2bf(o[2]); ov.w = f2bf(o[3]);
        reinterpret_cast<ushort4*>(outv)[(size_t)r * 256 + tid] = ov;
    }
}

extern "C" void kernel_launch(void* const* d_in, const int* in_sizes, int n_in,
                              void* d_out, int out_size, void* d_ws, size_t ws_size,
                              hipStream_t stream) {
    const void* q    = d_in[0];
    const void* attn = d_in[1];
    const void* pe   = d_in[2];
    int* flag = (int*)d_ws;
    float* li = (float*)((char*)d_ws + 256);

    const long L = 1024;
    const long rows = (long)in_sizes[1] / L;   // 49152
    const size_t ws_need = 256 + (size_t)rows * 64 * sizeof(float);

    if (ws_size >= ws_need) {
        // detect folded into k1; k1 block 0 publishes flag for k2
        cope_li<<<(int)(rows / 64), 256, 0, stream>>>(q, pe, li, flag);
        cope_row<<<(int)rows, 256, 0, stream>>>(attn, li, d_out, flag);
    } else {
        cope_detect<<<1, 256, 0, stream>>>((const unsigned short*)d_in[0], flag);
        cope_fused<<<(int)rows, 256, 0, stream>>>(q, attn, pe, d_out, flag);
    }
}